// Round 8
// baseline (62.551 us; speedup 1.0000x reference)
//
#include <hip/hip_runtime.h>
#include <hip/hip_bf16.h>
#include <hip/hip_cooperative_groups.h>
#include <math.h>

namespace cgrp = cooperative_groups;

typedef __attribute__((ext_vector_type(8))) short short8;
typedef __attribute__((ext_vector_type(4))) short short4v;
typedef __attribute__((ext_vector_type(4))) float f32x4;

#define LOG2E 1.44269504088896340736f

__device__ __forceinline__ short bf16bits(float x) {
    __hip_bfloat16 b = __float2bfloat16(x);
    short r;
    __builtin_memcpy(&r, &b, 2);
    return r;
}

// ---------------- single fused cooperative kernel ---------------------------
// Grid 2*(n_test/16) = 256 blocks x 1024 thr (16 waves) = 1 block/CU, fully
// co-resident (cooperative launch).
// Phase 1 (prep): wave gw = bid*16+wv preps rows 4gw..4gw+3 (f32->bf16 rows,
//   sq-norms, snh = {||y||^2, -0.5*log2e*w^2}), 4 rows/wave via lane =
//   sub(2b)*16+q(4b), float4 loads / short4 stores, 16-lane shfl reduce.
// grid.sync() — the single grid-wide release/acquire the cross-block
//   prep->main dependency fundamentally requires (replaces 2 kernel
//   boundaries; R2 lesson: per-BLOCK device fences are catastrophic, ONE
//   grid sync is the minimum).
// Phase 2 (main): blocks 0..127 own 16 test rows x all cols; wave wv covers
//   cols [wv*256,+256) in 16 steps of 16. K=64 via 2 chained
//   mfma_f32_16x16x32_bf16, fragments straight from global (L2-resident).
//   A: lane(l&15)=test row, k-chunk (l>>4)*8; B identical packing
//   (consistent k-bijection preserves the dot). C/D layout (HW-verified
//   m89): col=l&15, row=(l>>4)*4+reg. 16-lane shfl reduce -> 1KB LDS ->
//   threads 0..15 write out = log(sum)-Z. Blocks 128..255 exit after sync.
__global__ __launch_bounds__(1024) void kde_fused(
    const float* __restrict__ testX, const float* __restrict__ trainX,
    const float* __restrict__ w,
    __hip_bfloat16* __restrict__ testbf, __hip_bfloat16* __restrict__ trainbf,
    float* __restrict__ sqx, float2* __restrict__ snh,
    float* __restrict__ out, float Z, int n_test, int n_train)
{
    __shared__ float lds[16 * 16];   // [row][wave]

    const int tid  = threadIdx.x;
    const int wv   = tid >> 6;       // 0..15
    const int lane = tid & 63;

    // ---------------- phase 1: prep ----------------
    {
        const int gw  = blockIdx.x * 16 + wv;   // global wave id
        const int sub = lane >> 4;
        const int q   = lane & 15;
        const int row = gw * 4 + sub;
        if (row < n_test + n_train) {
            const float* src;
            __hip_bfloat16* dst;
            int rl;
            if (row < n_test) { src = testX;  dst = testbf;  rl = row; }
            else              { src = trainX; dst = trainbf; rl = row - n_test; }

            const float4 v = ((const float4*)src)[rl * 16 + q];
            short4v b = { bf16bits(v.x), bf16bits(v.y), bf16bits(v.z), bf16bits(v.w) };
            *(short4v*)(dst + rl * 64 + q * 4) = b;

            float s = v.x*v.x + v.y*v.y + v.z*v.z + v.w*v.w;
            #pragma unroll
            for (int m = 1; m < 16; m <<= 1) s += __shfl_xor(s, m);
            if (q == 0) {
                if (row < n_test) sqx[rl] = s;
                else {
                    float ww = w[rl];
                    snh[rl] = make_float2(s, -0.5f * LOG2E * ww * ww);
                }
            }
        }
    }

    cgrp::this_grid().sync();

    // ---------------- phase 2: main + finalize ----------------
    const int nrg = n_test >> 4;          // 128 row-groups
    if (blockIdx.x >= nrg) return;

    const int mbase = blockIdx.x * 16;
    const int cq    = lane & 15;          // col / A-row selector
    const int kg    = lane >> 4;          // k-chunk selector

    const int arow = mbase + cq;
    const short8 a0 = *(const short8*)(testbf + arow * 64 +      kg * 8);
    const short8 a1 = *(const short8*)(testbf + arow * 64 + 32 + kg * 8);

    float sxr[4];
    #pragma unroll
    for (int r = 0; r < 4; ++r) sxr[r] = sqx[mbase + kg * 4 + r];

    float s[4] = {0.f, 0.f, 0.f, 0.f};
    const int colbase = wv * 256;         // wave covers 256 cols in 16 steps

    #pragma unroll 4
    for (int step = 0; step < 16; ++step) {
        const int bcol = colbase + step * 16 + cq;
        const short8 b0 = *(const short8*)(trainbf + bcol * 64 +      kg * 8);
        const short8 b1 = *(const short8*)(trainbf + bcol * 64 + 32 + kg * 8);
        const float2 p  = snh[bcol];      // {||y||^2, -0.5*log2e*w^2}

        f32x4 acc = {0.f, 0.f, 0.f, 0.f};
        acc = __builtin_amdgcn_mfma_f32_16x16x32_bf16(a0, b0, acc, 0, 0, 0);
        acc = __builtin_amdgcn_mfma_f32_16x16x32_bf16(a1, b1, acc, 0, 0, 0);

        #pragma unroll
        for (int r = 0; r < 4; ++r) {
            float d2 = fmaxf(__builtin_fmaf(-2.0f, acc[r], sxr[r] + p.x), 0.0f);
            s[r] += __builtin_exp2f(d2 * p.y);
        }
    }

    #pragma unroll
    for (int m = 1; m < 16; m <<= 1) {
        #pragma unroll
        for (int r = 0; r < 4; ++r) s[r] += __shfl_xor(s[r], m);
    }
    if (cq == 0) {
        #pragma unroll
        for (int r = 0; r < 4; ++r)
            lds[(kg * 4 + r) * 16 + wv] = s[r];
    }
    __syncthreads();

    if (tid < 16) {
        float sum = 0.f;
        #pragma unroll
        for (int v = 0; v < 16; ++v) sum += lds[tid * 16 + v];
        out[mbase + tid] = __logf(sum) - Z;
    }
}

extern "C" void kernel_launch(void* const* d_in, const int* in_sizes, int n_in,
                              void* d_out, int out_size, void* d_ws, size_t ws_size,
                              hipStream_t stream) {
    const float* testX  = (const float*)d_in[0];
    const float* trainX = (const float*)d_in[1];
    const float* w      = (const float*)d_in[2];
    float* out = (float*)d_out;

    const int d = 64;
    int n_test  = in_sizes[0] / d;   // 2048
    int n_train = in_sizes[1] / d;   // 4096

    char* ws = (char*)d_ws;
    size_t off = 0;
    __hip_bfloat16* testbf  = (__hip_bfloat16*)(ws + off); off += (size_t)n_test  * d * 2;
    __hip_bfloat16* trainbf = (__hip_bfloat16*)(ws + off); off += (size_t)n_train * d * 2;
    float*  sqx = (float*)(ws + off);  off += (size_t)n_test * 4;
    float2* snh = (float2*)(ws + off); off += (size_t)n_train * 8;
    (void)ws_size; (void)n_in; (void)out_size;

    float Z = 0.5f * d * logf(2.0f * (float)M_PI) + logf((float)n_train);

    const int nblocks = 2 * (n_test / 16);   // 256: prep capacity for 16384 rows
    void* args[] = { &testX, &trainX, &w, &testbf, &trainbf,
                     &sqx, &snh, &out, &Z, &n_test, &n_train };
    hipLaunchCooperativeKernel((const void*)kde_fused, dim3(nblocks), dim3(1024),
                               args, 0, stream);
}

// Round 9
// 21.537 us; speedup vs baseline: 2.9043x; 2.9043x over previous
//
#include <hip/hip_runtime.h>
#include <hip/hip_bf16.h>
#include <math.h>

typedef __attribute__((ext_vector_type(8))) short short8;
typedef __attribute__((ext_vector_type(4))) short short4v;
typedef __attribute__((ext_vector_type(4))) float f32x4;

#define LOG2E 1.44269504088896340736f

__device__ __forceinline__ short bf16bits(float x) {
    __hip_bfloat16 b = __float2bfloat16(x);
    short r;
    __builtin_memcpy(&r, &b, 2);
    return r;
}

// ---------------- prep: f32 -> bf16 rows, row sq-norms, packed col params ----
// One wave handles 4 rows: lane = sub(2b)*16 + q(4b); row = wid*4+sub,
// dims q*4..q*4+3 via float4 load, short4 bf16 store. 16-lane shfl reduce
// for the sq-norm. Train rows also emit snh[j] = {||y||^2, -0.5*log2e*w^2}.
// Also zeroes out_sum[n_test] and counters[n_groups] (re-zeroed every call,
// so graph replays stay deterministic).
__global__ __launch_bounds__(256) void kde_prep(
    const float* __restrict__ testX, const float* __restrict__ trainX,
    const float* __restrict__ w,
    __hip_bfloat16* __restrict__ testbf, __hip_bfloat16* __restrict__ trainbf,
    float* __restrict__ sqx, float2* __restrict__ snh,
    float* __restrict__ out_sum, int* __restrict__ counters,
    int n_test, int n_train, int n_groups)
{
    const int tid  = threadIdx.x;

    const int zi = blockIdx.x * 256 + tid;
    if (zi < n_test) out_sum[zi] = 0.0f;
    else if (zi < n_test + n_groups) counters[zi - n_test] = 0;

    const int wid  = blockIdx.x * 4 + (tid >> 6);
    const int lane = tid & 63;
    const int sub  = lane >> 4;
    const int q    = lane & 15;
    const int row  = wid * 4 + sub;
    if (row >= n_test + n_train) return;

    const float* src;
    __hip_bfloat16* dst;
    int r_local;
    if (row < n_test) { src = testX;  dst = testbf;  r_local = row; }
    else              { src = trainX; dst = trainbf; r_local = row - n_test; }

    const float4 v = ((const float4*)src)[r_local * 16 + q];
    short4v b = { bf16bits(v.x), bf16bits(v.y), bf16bits(v.z), bf16bits(v.w) };
    *(short4v*)(dst + r_local * 64 + q * 4) = b;

    float s = v.x * v.x + v.y * v.y + v.z * v.z + v.w * v.w;
    #pragma unroll
    for (int m = 1; m < 16; m <<= 1) s += __shfl_xor(s, m);
    if (q == 0) {
        if (row < n_test) sqx[r_local] = s;
        else {
            float ww = w[r_local];
            snh[r_local] = make_float2(s, -0.5f * LOG2E * ww * ww);
        }
    }
}

// ---------------- main: MFMA cross + exp-sum + atomic combine + finalize ----
// Grid (n_test/16 = 128, 8 colchunks) = 1024 blocks x 256 thr (4 waves).
// Wave wv covers cols [cc*512 + wv*128, +128) in 8 steps of 16 (R1's proven
// geometry). K=64 via 2 chained mfma_f32_16x16x32_bf16, fragments straight
// from global (L2-resident). A: lane(l&15)=test row, k-chunk (l>>4)*8;
// B identical packing. C/D layout (HW-verified m89): col=l&15,
// row=(l>>4)*4+reg.
// Combine: 4 waves -> 64-entry LDS -> wave 0 does 16 device-scope atomicAdds
// (coherent point), s_waitcnt vmcnt(0) (wave-level: orders ALL 16 lanes'
// adds), then ONE counter atomic. The block observing old==gridDim.y-1 reads
// the sums with agent-scope atomic loads and writes log(sum)-Z. No
// __threadfence (R2 lesson: per-block device fences = L2-writeback storm);
// atomic->waitcnt->atomic gives the needed ordering for free.
__global__ __launch_bounds__(256, 8) void kde_main(
    const __hip_bfloat16* __restrict__ testbf,
    const __hip_bfloat16* __restrict__ trainbf,
    const float* __restrict__ sqx, const float2* __restrict__ snh,
    float* __restrict__ out_sum, int* __restrict__ counters,
    float* __restrict__ out, float Z)
{
    __shared__ float lds[16 * 4];   // [row][wave]

    const int mbase = blockIdx.x * 16;
    const int cc    = blockIdx.y;         // 0..7
    const int wv    = threadIdx.x >> 6;   // 0..3
    const int lane  = threadIdx.x & 63;
    const int cg    = lane & 15;          // col / A-row selector
    const int kg    = lane >> 4;          // k-chunk selector

    const int arow = mbase + cg;
    const short8 a0 = *(const short8*)(testbf + arow * 64 +      kg * 8);
    const short8 a1 = *(const short8*)(testbf + arow * 64 + 32 + kg * 8);

    float sxr[4];
    #pragma unroll
    for (int r = 0; r < 4; ++r) sxr[r] = sqx[mbase + kg * 4 + r];

    float s[4] = {0.f, 0.f, 0.f, 0.f};
    const int colbase = cc * 512 + wv * 128;

    #pragma unroll
    for (int step = 0; step < 8; ++step) {
        const int bcol = colbase + step * 16 + cg;
        const short8 b0 = *(const short8*)(trainbf + bcol * 64 +      kg * 8);
        const short8 b1 = *(const short8*)(trainbf + bcol * 64 + 32 + kg * 8);
        const float2 p  = snh[bcol];      // {||y||^2, -0.5*log2e*w^2}

        f32x4 acc = {0.f, 0.f, 0.f, 0.f};
        acc = __builtin_amdgcn_mfma_f32_16x16x32_bf16(a0, b0, acc, 0, 0, 0);
        acc = __builtin_amdgcn_mfma_f32_16x16x32_bf16(a1, b1, acc, 0, 0, 0);

        #pragma unroll
        for (int r = 0; r < 4; ++r) {
            float d2 = fmaxf(__builtin_fmaf(-2.0f, acc[r], sxr[r] + p.x), 0.0f);
            s[r] += __builtin_exp2f(d2 * p.y);
        }
    }

    // Reduce across the 16 col lanes (xor bits 0..3 keep kg fixed).
    #pragma unroll
    for (int m = 1; m < 16; m <<= 1) {
        #pragma unroll
        for (int r = 0; r < 4; ++r) s[r] += __shfl_xor(s[r], m);
    }
    if (cg == 0) {
        #pragma unroll
        for (int r = 0; r < 4; ++r)
            lds[(kg * 4 + r) * 4 + wv] = s[r];
    }
    __syncthreads();

    // Wave 0: combine 4 wave-partials, atomic-accumulate, maybe finalize.
    if (threadIdx.x < 64) {
        if (lane < 16) {
            float sum = lds[lane * 4 + 0] + lds[lane * 4 + 1]
                      + lds[lane * 4 + 2] + lds[lane * 4 + 3];
            atomicAdd(&out_sum[mbase + lane], sum);
        }
        asm volatile("s_waitcnt vmcnt(0)" ::: "memory");
        int old = 0;
        if (lane == 0)
            old = __hip_atomic_fetch_add(&counters[blockIdx.x], 1,
                                         __ATOMIC_RELAXED, __HIP_MEMORY_SCOPE_AGENT);
        old = __shfl(old, 0);
        if (old == (int)gridDim.y - 1 && lane < 16) {
            float ssum = __hip_atomic_load(&out_sum[mbase + lane],
                                           __ATOMIC_RELAXED, __HIP_MEMORY_SCOPE_AGENT);
            out[mbase + lane] = __logf(ssum) - Z;
        }
    }
}

extern "C" void kernel_launch(void* const* d_in, const int* in_sizes, int n_in,
                              void* d_out, int out_size, void* d_ws, size_t ws_size,
                              hipStream_t stream) {
    const float* testX  = (const float*)d_in[0];
    const float* trainX = (const float*)d_in[1];
    const float* w      = (const float*)d_in[2];
    float* out = (float*)d_out;

    const int d = 64;
    const int n_test  = in_sizes[0] / d;   // 2048
    const int n_train = in_sizes[1] / d;   // 4096
    const int n_cc    = 8;                 // col-chunks of 512
    const int n_groups = n_test / 16;      // 128

    char* ws = (char*)d_ws;
    size_t off = 0;
    __hip_bfloat16* testbf  = (__hip_bfloat16*)(ws + off); off += (size_t)n_test  * d * 2;
    __hip_bfloat16* trainbf = (__hip_bfloat16*)(ws + off); off += (size_t)n_train * d * 2;
    float*  sqx     = (float*)(ws + off);  off += (size_t)n_test * 4;
    float2* snh     = (float2*)(ws + off); off += (size_t)n_train * 8;
    float*  out_sum = (float*)(ws + off);  off += (size_t)n_test * 4;
    int*    counters = (int*)(ws + off);   off += (size_t)n_groups * 4;
    (void)ws_size; (void)n_in; (void)out_size;

    const float Z = 0.5f * d * logf(2.0f * (float)M_PI) + logf((float)n_train);

    const int rows = n_test + n_train;                 // 6144
    kde_prep<<<rows / 16, 256, 0, stream>>>(
        testX, trainX, w, testbf, trainbf, sqx, snh,
        out_sum, counters, n_test, n_train, n_groups);

    dim3 grid(n_groups, n_cc);
    kde_main<<<grid, 256, 0, stream>>>(
        testbf, trainbf, sqx, snh, out_sum, counters, out, Z);
}